// Round 4
// baseline (258.495 us; speedup 1.0000x reference)
//
#include <hip/hip_runtime.h>

typedef __bf16 bfvec8 __attribute__((ext_vector_type(8)));
typedef float f32x4 __attribute__((ext_vector_type(4)));
typedef unsigned short u16x8 __attribute__((ext_vector_type(8)));
typedef unsigned int u32;

constexpr int C_IN = 128, Wd = 56, Hd = 56, HW = 3136, K_OUT = 256, N_IMG = 32;
constexpr int KKTOT = 1152;      // 128*9
constexpr int WP = 58;           // padded H/W
constexpr size_t XP_ELEMS = (size_t)N_IMG * WP * WP * C_IN;   // 13,776,896
constexpr size_t XP_BYTES = XP_ELEMS * 2;                     // 27,553,792
constexpr size_t WT_ELEMS = (size_t)9 * 4 * 256 * 32;         // 294,912

__device__ inline unsigned short f2bf(float f) {
    union { float f; unsigned u; } v; v.f = f;
    unsigned u = v.u;
    u += 0x7fffu + ((u >> 16) & 1u);   // round-to-nearest-even
    return (unsigned short)(u >> 16);
}

__device__ inline void gld16(const void* g, void* l) {
    __builtin_amdgcn_global_load_lds(
        (const __attribute__((address_space(1))) u32*)g,
        (__attribute__((address_space(3))) u32*)l, 16, 0, 0);
}

// ---- Fused pre-pass ------------------------------------------------------
// blocks 0..1791   : x NCHW fp32 -> halo-padded NHWC bf16 (interior rows)
// blocks 1792..1823: zero the halo of image n (1.9 MB total, not 27.5)
// blocks 1824..1887: weight OIHW fp32 -> packed bf16, o=((rs*4+ch)*256+n)*32+kk
__global__ __launch_bounds__(256) void prep(const float* __restrict__ x,
                                            const float* __restrict__ w,
                                            unsigned short* __restrict__ xp,
                                            unsigned short* __restrict__ wt) {
    const int bx = blockIdx.x, tid = threadIdx.x;
    if (bx < 1792) {
        __shared__ unsigned short T[Wd * C_IN];   // 14336 B, XOR-swizzled
        const int n = bx / Hd, h = bx - n * Hd;
        const float* src = x + (size_t)n * C_IN * HW + h * Wd;
        #pragma unroll
        for (int k = 0; k < 7; ++k) {
            int idx = tid + k * 256;              // float4 index 0..1791
            int c = idx / 14, w4 = idx - c * 14;
            const float4 v = *(const float4*)(src + (size_t)c * HW + w4 * 4);
            const int sw = (w4 & 15) * 8;
            T[(w4 * 4 + 0) * C_IN + (c ^ sw)] = f2bf(v.x);
            T[(w4 * 4 + 1) * C_IN + (c ^ sw)] = f2bf(v.y);
            T[(w4 * 4 + 2) * C_IN + (c ^ sw)] = f2bf(v.z);
            T[(w4 * 4 + 3) * C_IN + (c ^ sw)] = f2bf(v.w);
        }
        __syncthreads();
        unsigned short* dst = xp + ((size_t)(n * WP + h + 1) * WP + 1) * C_IN;
        const u16x8* s8 = (const u16x8*)T;
        u16x8* d8 = (u16x8*)dst;
        #pragma unroll
        for (int k = 0; k < 4; ++k) {
            int idx = tid + k * 256;
            if (idx < 896) {
                int ww = idx >> 4, j8 = idx & 15;
                d8[idx] = s8[ww * 16 + (j8 ^ ((ww >> 2) & 15))];
            }
        }
    } else if (bx < 1824) {
        const int n = bx - 1792;
        u16x8 z = {0, 0, 0, 0, 0, 0, 0, 0};
        u16x8* base = (u16x8*)(xp + (size_t)n * WP * WP * C_IN);
        #pragma unroll
        for (int it = 0; it < 15; ++it) {
            int v = tid + it * 256;
            if (v < 928) base[v] = z;                               // row h=0
            else if (v < 1856) base[52896 + (v - 928)] = z;         // row h=57
            else if (v < 3648) {                                    // cols 0,57
                int u = v - 1856, seg = u >> 4, j = u & 15;
                int h = 1 + (seg >> 1), side = seg & 1;
                base[(h * WP + side * 57) * 16 + j] = z;
            }
        }
    } else {
        const int o0 = (bx - 1824) * 4608 + tid;
        #pragma unroll
        for (int j = 0; j < 18; ++j) {
            int o = o0 + j * 256;
            int kk = o & 31, n = (o >> 5) & 255, r2 = o >> 13;
            int ch = r2 & 3, rs = r2 >> 2;
            wt[o] = f2bf(w[(size_t)n * KKTOT + (ch * 32 + kk) * 9 + rs]);
        }
    }
}

// ---- Main GEMM: 128x256 tile, wave-tile 64x128, dbuf single-barrier ------
// LDS XOR swizzle: 16B-slot (row r, cs) holds k-chunk cs ^ ((r>>1)&3),
// realized by per-lane SOURCE address in global_load_lds.
__global__ __launch_bounds__(256) void conv_gemm(
    const unsigned short* __restrict__ xp, const unsigned short* __restrict__ wt,
    const float* __restrict__ bias, float* __restrict__ out)
{
    __shared__ __align__(16) unsigned short As[2][128 * 32];  // 2 x 8 KB
    __shared__ __align__(16) unsigned short Bs[2][256 * 32];  // 2 x 16 KB

    const int tid = threadIdx.x;
    const int mtile = blockIdx.x * 128;

    const int cg8 = ((tid & 3) ^ ((tid >> 3) & 3)) * 8;   // swizzled src chunk

    const unsigned short *gA0, *gA1;
    {
        int m = mtile + (tid >> 2);
        int ni = m / HW, hw = m - ni * HW, h = hw / Wd, w = hw - h * Wd;
        gA0 = xp + ((size_t)(ni * WP + h + 1) * WP + (w + 1)) * C_IN + cg8;
        m += 64;
        ni = m / HW; hw = m - ni * HW; h = hw / Wd; w = hw - h * Wd;
        gA1 = xp + ((size_t)(ni * WP + h + 1) * WP + (w + 1)) * C_IN + cg8;
    }
    const size_t bbase = (size_t)(tid & 0xFC) * 8 + cg8;   // row*32 + swz chunk

    const int wave = tid >> 6, lane = tid & 63;
    const int wrow = (wave & 1) * 64;          // m-offset of wave tile
    const int wcol = (wave >> 1) * 128;        // n-offset of wave tile
    const int r16 = lane & 15, quad = lane >> 4;
    const int qsw = (quad ^ ((r16 >> 1) & 3)) * 8;

    const f32x4 zero4 = {0.f, 0.f, 0.f, 0.f};
    f32x4 acc[4][8];
    #pragma unroll
    for (int i = 0; i < 4; ++i)
        #pragma unroll
        for (int j = 0; j < 8; ++j)
            acc[i][j] = zero4;

    auto stage = [&](int step, int b) {
        const int rs = step >> 2, ch = step & 3;
        const int dr = rs / 3 - 1, dc = rs % 3 - 1;
        const int aoff = (dr * WP + dc) * C_IN + ch * 32;          // uniform
        const size_t boff = (size_t)((rs * 4 + ch) * 8192) + bbase;
        unsigned short* a = &As[b][0] + tid * 8;
        unsigned short* bl = &Bs[b][0] + tid * 8;
        gld16(gA0 + aoff, a);
        gld16(gA1 + aoff, a + 2048);
        gld16(wt + boff,        bl);
        gld16(wt + boff + 2048, bl + 2048);
        gld16(wt + boff + 4096, bl + 4096);
        gld16(wt + boff + 6144, bl + 6144);
    };

    stage(0, 0);
    int cur = 0;
    for (int step = 0; step < 36; ++step) {
        __syncthreads();                // drains vmcnt: buf[cur] staged; also
                                        // all waves done reading buf[cur^1]
        if (step < 35) stage(step + 1, cur ^ 1);   // latency hidden by compute

        bfvec8 af[4], bf[8];
        #pragma unroll
        for (int mi = 0; mi < 4; ++mi)
            af[mi] = *(const bfvec8*)&As[cur][(wrow + mi * 16 + r16) * 32 + qsw];
        #pragma unroll
        for (int ni = 0; ni < 8; ++ni)
            bf[ni] = *(const bfvec8*)&Bs[cur][(wcol + ni * 16 + r16) * 32 + qsw];

        #pragma unroll
        for (int mi = 0; mi < 4; ++mi)
            #pragma unroll
            for (int ni = 0; ni < 8; ++ni)
                acc[mi][ni] = __builtin_amdgcn_mfma_f32_16x16x32_bf16(
                    af[mi], bf[ni], acc[mi][ni], 0, 0, 0);
        cur ^= 1;
    }

    // epilogue: D col=lane&15 -> k, row=quad*4+i -> m; f32x4 stores (3136%4==0)
    #pragma unroll
    for (int ni = 0; ni < 8; ++ni) {
        const int k = wcol + ni * 16 + r16;
        const float bb = bias[k];
        #pragma unroll
        for (int mi = 0; mi < 4; ++mi) {
            const int mb  = mtile + wrow + mi * 16 + quad * 4;
            const int ne  = mb / HW;
            const int hwe = mb - ne * HW;
            f32x4 v;
            #pragma unroll
            for (int i = 0; i < 4; ++i) v[i] = acc[mi][ni][i] + bb;
            *(f32x4*)(out + ((size_t)ne * K_OUT + k) * HW + hwe) = v;
        }
    }
}

extern "C" void kernel_launch(void* const* d_in, const int* in_sizes, int n_in,
                              void* d_out, int out_size, void* d_ws, size_t ws_size,
                              hipStream_t stream) {
    const float* x    = (const float*)d_in[0];
    const float* wgt  = (const float*)d_in[1];
    const float* bias = (const float*)d_in[2];
    float* out = (float*)d_out;

    unsigned short* xp = (unsigned short*)d_ws;
    unsigned short* wt = (unsigned short*)((char*)d_ws + XP_BYTES);

    prep<<<dim3(1888), dim3(256), 0, stream>>>(x, wgt, xp, wt);
    conv_gemm<<<dim3(784), dim3(256), 0, stream>>>(xp, wt, bias, out);
}